// Round 1
// 255.905 us; speedup vs baseline: 1.0228x; 1.0228x over previous
//
#include <hip/hip_runtime.h>

typedef _Float16 f16;
typedef _Float16 h8_t __attribute__((ext_vector_type(8)));
typedef _Float16 h4_t __attribute__((ext_vector_type(4)));
typedef float f32x4 __attribute__((ext_vector_type(4)));
typedef float f32x16 __attribute__((ext_vector_type(16)));

#define BS 16
#define DA 512
#define SL 1024
#define NH 8
#define DH 64

// direct global->LDS DMA, 16B per lane. HW dest = firstlane(l) + lane*16,
// so lane i's lds pointer must equal base + i*16 (linear layout).
__device__ __forceinline__ void gload_lds16(const void* g, void* l) {
  __builtin_amdgcn_global_load_lds((const __attribute__((address_space(1))) void*)g,
                                   (__attribute__((address_space(3))) void*)l, 16, 0, 0);
}

// ---------------------------------------------------------------------------
// P0: prep pass.
//  blocks [0,2048):   transpose+convert X [b][c][s] f32 -> Xt [b][s][c] f16,
//                     tile 64c x 128s through LDS (once per tile, vs 4x in the
//                     old fused kernel).
//  blocks [2048,2112): convert k_w / v_w f32 -> f16 (same [o][c] layout).
// ---------------------------------------------------------------------------
__global__ __launch_bounds__(256) void prep_kernel(
    const float* __restrict__ k_in, const float* __restrict__ v_in,
    const float* __restrict__ k_w, const float* __restrict__ v_w,
    f16* __restrict__ Kt, f16* __restrict__ Vt,
    f16* __restrict__ kwh, f16* __restrict__ vwh) {
  const int blk = blockIdx.x;
  const int t = threadIdx.x;
  if (blk < 2048) {
    const int which = blk >> 10;        // 0: k_in, 1: v_in
    const int r = blk & 1023;
    const int b = r >> 6;               // 0..15
    const int c0 = ((r >> 3) & 7) * 64; // 8 c-tiles
    const int s0 = (r & 7) * 128;       // 8 s-tiles
    const float* src = which ? v_in : k_in;
    f16* dst = which ? Vt : Kt;
    __shared__ __align__(16) float Xf32[64 * 132];
    // phase 1: read [64 c][128 s] f32, coalesced along s
#pragma unroll
    for (int p = 0; p < 8; ++p) {
      const int idx = p * 256 + t;
      const int cc = idx >> 5, s4 = (idx & 31) * 4;
      const float4 v = *(const float4*)&src[((size_t)b * DA + c0 + cc) * SL + s0 + s4];
      *(float4*)&Xf32[cc * 132 + s4] = v;
    }
    __syncthreads();
    // phase 2: transposed read (2-way conflicts only), f16 convert, 64B/thread
    // contiguous global stores (lane pairs cover a full 128B line per s-row)
    const int srow = t >> 1, cb = (t & 1) * 32;
#pragma unroll
    for (int g = 0; g < 4; ++g) {
      h8_t h;
#pragma unroll
      for (int u = 0; u < 8; ++u) h[u] = (f16)Xf32[(cb + g * 8 + u) * 132 + srow];
      *(h8_t*)&dst[((size_t)b * SL + s0 + srow) * DA + c0 + cb + g * 8] = h;
    }
  } else {
    const int r = blk - 2048;           // 0..63
    const int wsel = r >> 5;            // 0: k_w, 1: v_w
    const float* src = wsel ? v_w : k_w;
    f16* dst = wsel ? vwh : kwh;
    const int base = (r & 31) * 8192;   // 8192 f32 per block, 32 blocks/weight
#pragma unroll
    for (int p = 0; p < 4; ++p) {
      const int i = base + p * 2048 + t * 8;
      const float4 a = *(const float4*)&src[i];
      const float4 c = *(const float4*)&src[i + 4];
      h8_t h;
      h[0] = (f16)a.x; h[1] = (f16)a.y; h[2] = (f16)a.z; h[3] = (f16)a.w;
      h[4] = (f16)c.x; h[5] = (f16)c.y; h[6] = (f16)c.z; h[7] = (f16)c.w;
      *(h8_t*)&dst[i] = h;
    }
  }
}

// ---------------------------------------------------------------------------
// K1: projection GEMM, m97 structure. C[m][n] = sum_k A[m][k]*B[n][k], all f16
// operands pre-converted (prep pass), staged via global_load_lds (16B), 128^2
// tile, BK=32, 4 waves x 64x64, 2 barriers per K-step, 16 MFMA 16x16x32/wave.
// MODE 0 (k-proj): A = k_wh [o][c], B = Kt[b] [s][c], out kp[b][s][o] + k_b(m)
// MODE 1 (v-proj): A = Vt[b] [s][c], B = v_wh [o][c], out vp[b][o][s] + v_b(n)
// grid (M/128, N/128, BS), block 256. Epilogue identical to previous kernel.
// ---------------------------------------------------------------------------
template <int MODE>
__global__ __launch_bounds__(256) void proj_gemm(const f16* __restrict__ Ag,
                                                 const f16* __restrict__ Bg,
                                                 const float* __restrict__ bias,
                                                 f16* __restrict__ outg) {
  constexpr int MT = MODE ? SL : DA;
  constexpr int NT = MODE ? DA : SL;
  __shared__ __align__(16) f16 Al[128 * 32];
  __shared__ __align__(16) f16 Bl[128 * 32];
  const int b = blockIdx.z;
  const int m0 = blockIdx.x * 128, n0 = blockIdx.y * 128;
  const int t = threadIdx.x;
  const int lane = t & 63, w = t >> 6, lr = lane & 15, lq = lane >> 4;
  const int wm = (w >> 1) * 64, wn = (w & 1) * 64;

  const f16* Arow = Ag + (MODE ? (size_t)b * SL * DA : 0) + (size_t)m0 * DA;
  const f16* Brow = Bg + (MODE ? 0 : (size_t)b * SL * DA) + (size_t)n0 * DA;

  const int rr = t >> 2;          // 0..63: tile row (lower half)
  const int c8 = (t & 3) * 8;     // f16 col within the 32-wide K-slice

  f32x4 acc[4][4] = {};

  for (int kt = 0; kt < 16; ++kt) {
    const int c0 = kt * 32;
    __syncthreads();  // prev iter's LDS reads done
    gload_lds16(Arow + (size_t)rr * DA + c0 + c8, Al + t * 8);
    gload_lds16(Arow + (size_t)(64 + rr) * DA + c0 + c8, Al + 2048 + t * 8);
    gload_lds16(Brow + (size_t)rr * DA + c0 + c8, Bl + t * 8);
    gload_lds16(Brow + (size_t)(64 + rr) * DA + c0 + c8, Bl + 2048 + t * 8);
    __syncthreads();  // compiler drains vmcnt(0) before the barrier
    h8_t af[4], bf[4];
#pragma unroll
    for (int i = 0; i < 4; ++i) af[i] = *(const h8_t*)&Al[(wm + i * 16 + lr) * 32 + lq * 8];
#pragma unroll
    for (int j = 0; j < 4; ++j) bf[j] = *(const h8_t*)&Bl[(wn + j * 16 + lr) * 32 + lq * 8];
#pragma unroll
    for (int i = 0; i < 4; ++i)
#pragma unroll
      for (int j = 0; j < 4; ++j)
        acc[i][j] = __builtin_amdgcn_mfma_f32_16x16x32_f16(af[i], bf[j], acc[i][j], 0, 0, 0);
  }

  // epilogue: D row = gm (4 consecutive per lane -> 8B f16 stores), col = gn
#pragma unroll
  for (int i = 0; i < 4; ++i) {
    const int gmb = m0 + wm + i * 16 + lq * 4;
    float bm[4] = {0.f, 0.f, 0.f, 0.f};
    if (MODE == 0) {
      const float4 b4 = *(const float4*)&bias[gmb];
      bm[0] = b4.x; bm[1] = b4.y; bm[2] = b4.z; bm[3] = b4.w;
    }
#pragma unroll
    for (int j = 0; j < 4; ++j) {
      const int gn = n0 + wn + j * 16 + lr;
      const float bn = (MODE == 1) ? bias[gn] : 0.f;
      h4_t hv;
#pragma unroll
      for (int r = 0; r < 4; ++r) {
        const float val = acc[i][j][r] + (MODE == 0 ? bm[r] : bn);
        hv[r] = (f16)val;
      }
      *(h4_t*)&outg[((size_t)b * NT + gn) * MT + gmb] = hv;
    }
  }
}

// ---------------------------------------------------------------------------
// Fallback: previous fused transpose+projection kernel (used only if the
// workspace is too small for the split-pass path). Verified correct.
// ---------------------------------------------------------------------------
template <int MODE>
__global__ __launch_bounds__(256) void fused_proj(const float* __restrict__ Wg,
                                                  const float* __restrict__ Xin,
                                                  const float* __restrict__ bias,
                                                  f16* __restrict__ outg) {
  constexpr int MT = MODE ? SL : DA;
  constexpr int NT = MODE ? DA : SL;
  __shared__ f16 Wl[128 * 40];     // [o][c] f16
  __shared__ f16 Xl[128 * 40];     // [s][c] f16 (transposed)
  __shared__ float Xf32[32 * 132]; // [c][s] staging
  const int b = blockIdx.z;
  const int m0 = blockIdx.x * 128;
  const int n0 = blockIdx.y * 128;
  const int o_base = MODE ? n0 : m0;
  const int s_base = MODE ? m0 : n0;
  const int t = threadIdx.x;
  const int w = t >> 6, lane = t & 63, lr = lane & 15, lq = lane >> 4;
  const int wm = (w >> 1) * 64, wn = (w & 1) * 64;

  f32x4 acc[4][4] = {};

  for (int kt = 0; kt < 16; ++kt) {
    const int c0 = kt * 32;
    __syncthreads();
#pragma unroll
    for (int p = 0; p < 4; ++p) {
      const int idx = p * 256 + t;
      const int row = idx >> 3, cq = (idx & 7) * 4;
      const float4 v = *(const float4*)&Wg[(size_t)(o_base + row) * DA + c0 + cq];
      h4_t hv;
      hv[0] = (f16)v.x; hv[1] = (f16)v.y; hv[2] = (f16)v.z; hv[3] = (f16)v.w;
      *(h4_t*)&Wl[row * 40 + cq] = hv;
    }
#pragma unroll
    for (int p = 0; p < 4; ++p) {
      const int idx = p * 256 + t;
      const int cc = idx >> 5, s4 = (idx & 31) * 4;
      const float4 v = *(const float4*)&Xin[((size_t)b * DA + c0 + cc) * SL + s_base + s4];
      *(float4*)&Xf32[cc * 132 + s4] = v;
    }
    __syncthreads();
    {
      const int srow = t >> 1, cb = (t & 1) * 16;
      h8_t lo, hi;
#pragma unroll
      for (int u = 0; u < 8; ++u) lo[u] = (f16)Xf32[(cb + u) * 132 + srow];
#pragma unroll
      for (int u = 0; u < 8; ++u) hi[u] = (f16)Xf32[(cb + 8 + u) * 132 + srow];
      *(h8_t*)&Xl[srow * 40 + cb] = lo;
      *(h8_t*)&Xl[srow * 40 + cb + 8] = hi;
    }
    __syncthreads();
    const f16* Alp = MODE ? Xl : Wl;
    const f16* Blp = MODE ? Wl : Xl;
    h8_t af[4], bf[4];
#pragma unroll
    for (int i = 0; i < 4; ++i) af[i] = *(const h8_t*)&Alp[(wm + i * 16 + lr) * 40 + lq * 8];
#pragma unroll
    for (int j = 0; j < 4; ++j) bf[j] = *(const h8_t*)&Blp[(wn + j * 16 + lr) * 40 + lq * 8];
#pragma unroll
    for (int i = 0; i < 4; ++i)
#pragma unroll
      for (int j = 0; j < 4; ++j)
        acc[i][j] = __builtin_amdgcn_mfma_f32_16x16x32_f16(af[i], bf[j], acc[i][j], 0, 0, 0);
  }

#pragma unroll
  for (int i = 0; i < 4; ++i) {
    const int gmb = m0 + wm + i * 16 + lq * 4;
    float bm[4] = {0.f, 0.f, 0.f, 0.f};
    if (MODE == 0) {
      const float4 b4 = *(const float4*)&bias[gmb];
      bm[0] = b4.x; bm[1] = b4.y; bm[2] = b4.z; bm[3] = b4.w;
    }
#pragma unroll
    for (int j = 0; j < 4; ++j) {
      const int gn = n0 + wn + j * 16 + lr;
      const float bn = (MODE == 1) ? bias[gn] : 0.f;
      h4_t hv;
#pragma unroll
      for (int r = 0; r < 4; ++r) {
        const float val = acc[i][j][r] + (MODE == 0 ? bm[r] : bn);
        hv[r] = (f16)val;
      }
      *(h4_t*)&outg[((size_t)b * NT + gn) * MT + gmb] = hv;
    }
  }
}

// ---------------------------------------------------------------------------
// K2: fused flash attention. grid (BS*NH, SL/256), block 256 (4 waves x 64 i).
// UNCHANGED from previous verified version.
// ---------------------------------------------------------------------------
__global__ __launch_bounds__(256, 2) void attn_kernel(
    const float* __restrict__ qg, const f16* __restrict__ kp, const f16* __restrict__ vp,
    const float* __restrict__ gamma, const float* __restrict__ gbns,
    const int* __restrict__ maskg, float* __restrict__ outg) {
  __shared__ __align__(16) char smem[36864];
  f16* KV = (f16*)smem;       // 2 bufs x (K[64][72] + V[64][72]) f16
  float* Osh = (float*)smem;  // epilogue overlay [32 d][256 i] f32

  const int bh = blockIdx.x, b = bh >> 3, h = bh & 7;
  const int i0 = blockIdx.y * 256;
  const int t = threadIdx.x, w = t >> 6, lane = t & 63;
  const int l5 = lane & 31, hf = lane >> 5;
  const float scale = gamma[h] / gbns[h] * 1.44269504088896f;  // GBN scale * log2(e)

  // ---- Q fragments straight from global (B-operand: n=i, k=d)
  h8_t qf[2][4];
#pragma unroll
  for (int im = 0; im < 2; ++im)
#pragma unroll
    for (int ks = 0; ks < 4; ++ks) {
      h8_t v;
#pragma unroll
      for (int u = 0; u < 8; ++u) {
        const int d = ks * 16 + hf * 8 + u;
        v[u] = (f16)(qg[((size_t)b * DA + h * DH + d) * SL + i0 + w * 64 + im * 32 + l5] * scale);
      }
      qf[im][ks] = v;
    }

  const int srow = t >> 3;        // 0..31 (p adds 32)
  const int c8 = (t & 7) * 8;

  // ---- stage tile 0 (K rows sigma-permuted: swap bits 2,3)
  uint4 rk[2], rv[2];
#pragma unroll
  for (int p = 0; p < 2; ++p) {
    const int row = p * 32 + srow;
    rk[p] = *(const uint4*)&kp[((size_t)b * SL + row) * DA + h * DH + c8];
    rv[p] = *(const uint4*)&vp[((size_t)b * DA + h * DH + row) * SL + c8];
  }
  {
    f16* K0 = KV;
    f16* V0 = KV + 4608;
#pragma unroll
    for (int p = 0; p < 2; ++p) {
      const int row = p * 32 + srow;
      const int rowp = (row & ~12) | ((row & 4) << 1) | ((row & 8) >> 1);
      *(uint4*)&K0[rowp * 72 + c8] = rk[p];
      *(uint4*)&V0[row * 72 + c8] = rv[p];
    }
  }
  __syncthreads();

  float m_i[2] = {-3e38f, -3e38f}, l_i[2] = {0.f, 0.f};
  f32x16 acc[2][2] = {};  // [im][nd]: rows d = nd*32 + r(e,hf), col i = lane

  for (int jt = 0; jt < 16; ++jt) {
    const int j0 = jt * 64;
    const f16* Kc = KV + (jt & 1) * 9216;
    const f16* Vc = Kc + 4608;

    // prefetch next tile into regs (written at loop bottom)
    if (jt < 15) {
      const int jn = j0 + 64;
#pragma unroll
      for (int p = 0; p < 2; ++p) {
        const int row = p * 32 + srow;
        rk[p] = *(const uint4*)&kp[((size_t)b * SL + jn + row) * DA + h * DH + c8];
        rv[p] = *(const uint4*)&vp[((size_t)b * DA + h * DH + row) * SL + jn + c8];
      }
    }
    // key-mask quads, sigma-mapped: reg e=q*4+r <-> j = mj*32+16(q>>1)+8hf+4(q&1)+r
    int4 mq[2][4];
#pragma unroll
    for (int mj = 0; mj < 2; ++mj)
#pragma unroll
      for (int q = 0; q < 4; ++q)
        mq[mj][q] = *(const int4*)&maskg[b * SL + j0 + mj * 32 + (q >> 1) * 16 + hf * 8 + (q & 1) * 4];

    // S^T = K * Q^T : rows = permuted K rows, cols = i
    f32x16 sa[2][2] = {};
#pragma unroll
    for (int ks = 0; ks < 4; ++ks)
#pragma unroll
      for (int mj = 0; mj < 2; ++mj) {
        const h8_t kf = *(const h8_t*)&Kc[(mj * 32 + l5) * 72 + ks * 16 + hf * 8];
#pragma unroll
        for (int im = 0; im < 2; ++im)
          sa[im][mj] = __builtin_amdgcn_mfma_f32_32x32x16_f16(kf, qf[im][ks], sa[im][mj], 0, 0, 0);
      }

    // key mask
#pragma unroll
    for (int mj = 0; mj < 2; ++mj)
#pragma unroll
      for (int q = 0; q < 4; ++q) {
        const int4 m4 = mq[mj][q];
#pragma unroll
        for (int im = 0; im < 2; ++im) {
          if (m4.x) sa[im][mj][q * 4 + 0] = -1e9f;
          if (m4.y) sa[im][mj][q * 4 + 1] = -1e9f;
          if (m4.z) sa[im][mj][q * 4 + 2] = -1e9f;
          if (m4.w) sa[im][mj][q * 4 + 3] = -1e9f;
        }
      }

    // online softmax, two independent chains; exp2 domain; per-lane i = l5
    float alpha[2];
#pragma unroll
    for (int im = 0; im < 2; ++im) {
      float mx = sa[im][0][0];
#pragma unroll
      for (int e = 1; e < 16; ++e) mx = fmaxf(mx, sa[im][0][e]);
#pragma unroll
      for (int e = 0; e < 16; ++e) mx = fmaxf(mx, sa[im][1][e]);
      mx = fmaxf(mx, __shfl_xor(mx, 32));
      const float mn = fmaxf(m_i[im], mx);
      alpha[im] = __builtin_amdgcn_exp2f(m_i[im] - mn);
      m_i[im] = mn;
      float rs = 0.f;
#pragma unroll
      for (int mj = 0; mj < 2; ++mj)
#pragma unroll
        for (int e = 0; e < 16; ++e) {
          const float pv = __builtin_amdgcn_exp2f(sa[im][mj][e] - mn);
          sa[im][mj][e] = pv;
          rs += pv;
        }
      rs += __shfl_xor(rs, 32);
      l_i[im] = l_i[im] * alpha[im] + rs;
      // rescale O accumulator: per-lane scalar!
#pragma unroll
      for (int nd = 0; nd < 2; ++nd)
#pragma unroll
        for (int e = 0; e < 16; ++e) acc[im][nd][e] *= alpha[im];
    }

    // O^T += V^T * P^T : A = V^T[d][j] from LDS, B = P^T straight from regs
    // (sigma cancellation: B slot k holds logical j = k)
#pragma unroll
    for (int jk = 0; jk < 4; ++jk) {
      const int mj = jk >> 1, g = jk & 1;
      h8_t pf[2];
#pragma unroll
      for (int im = 0; im < 2; ++im) {
        h8_t pk;
#pragma unroll
        for (int u = 0; u < 8; ++u) pk[u] = (f16)sa[im][mj][g * 8 + u];
        pf[im] = pk;
      }
#pragma unroll
      for (int nd = 0; nd < 2; ++nd) {
        const h8_t vf = *(const h8_t*)&Vc[(nd * 32 + l5) * 72 + jk * 16 + hf * 8];
#pragma unroll
        for (int im = 0; im < 2; ++im)
          acc[im][nd] = __builtin_amdgcn_mfma_f32_32x32x16_f16(vf, pf[im], acc[im][nd], 0, 0, 0);
      }
    }

    // write prefetched tile into the other buffer; ONE barrier per tile
    if (jt < 15) {
      f16* Kn = KV + ((jt + 1) & 1) * 9216;
      f16* Vn = Kn + 4608;
#pragma unroll
      for (int p = 0; p < 2; ++p) {
        const int row = p * 32 + srow;
        const int rowp = (row & ~12) | ((row & 4) << 1) | ((row & 8) >> 1);
        *(uint4*)&Kn[rowp * 72 + c8] = rk[p];
        *(uint4*)&Vn[row * 72 + c8] = rv[p];
      }
      __syncthreads();
    }
  }

  // ---- epilogue: per-lane 1/l (0 for masked query rows), LDS bounce per nd
  float fac[2];
#pragma unroll
  for (int im = 0; im < 2; ++im) {
    const int mo = maskg[b * SL + i0 + w * 64 + im * 32 + l5];
    fac[im] = mo ? 0.f : 1.f / l_i[im];
  }
  __syncthreads();  // all waves done reading KV before Osh overlay

#pragma unroll
  for (int nd = 0; nd < 2; ++nd) {
    // scatter acc into Osh [d_local][i_block] (2-way conflicts only)
#pragma unroll
    for (int im = 0; im < 2; ++im)
#pragma unroll
      for (int e = 0; e < 16; ++e) {
        const int dl = (e & 3) + 8 * (e >> 2) + 4 * hf;
        Osh[dl * 256 + w * 64 + im * 32 + l5] = acc[im][nd][e] * fac[im];
      }
    __syncthreads();
    // coalesced store: 1KB contiguous per d-row
#pragma unroll
    for (int pass = 0; pass < 8; ++pass) {
      const int row = pass * 4 + w;
      const int i4 = lane * 4;
      const float4 o = *(const float4*)&Osh[row * 256 + i4];
      *(float4*)&outg[((size_t)b * DA + h * DH + nd * 32 + row) * SL + i0 + i4] = o;
    }
    __syncthreads();  // before next nd pass overwrites Osh
  }
}

// ---------------------------------------------------------------------------
extern "C" void kernel_launch(void* const* d_in, const int* in_sizes, int n_in,
                              void* d_out, int out_size, void* d_ws, size_t ws_size,
                              hipStream_t stream) {
  const float* q     = (const float*)d_in[0];
  const float* k_in  = (const float*)d_in[1];
  const float* v_in  = (const float*)d_in[2];
  const float* k_w   = (const float*)d_in[3];
  const float* k_b   = (const float*)d_in[4];
  const float* v_w   = (const float*)d_in[5];
  const float* v_b   = (const float*)d_in[6];
  const float* gamma = (const float*)d_in[7];
  const float* gbns  = (const float*)d_in[10];  // gbn_bias/gbn_m cancel under softmax
  const int*   mask  = (const int*)d_in[11];
  float* out = (float*)d_out;

  const size_t NEL = (size_t)BS * SL * DA;
  f16* kpw = (f16*)d_ws;        // k projection, [b][s][o], 16 MiB
  f16* vpw = kpw + NEL;         // v projection, [b][o][s], 16 MiB

  const size_t need = NEL * 2 * 4 + (size_t)DA * DA * 2 * 2;  // 64 MiB + 1 MiB
  if (ws_size >= need) {
    f16* Kt  = vpw + NEL;       // k_in transposed+converted, [b][s][c], 16 MiB
    f16* Vt  = Kt + NEL;        // v_in transposed+converted, [b][s][c], 16 MiB
    f16* kwh = Vt + NEL;        // k_w f16, [o][c]
    f16* vwh = kwh + (size_t)DA * DA;
    prep_kernel<<<dim3(2112), 256, 0, stream>>>(k_in, v_in, k_w, v_w, Kt, Vt, kwh, vwh);
    proj_gemm<0><<<dim3(4, 8, BS), 256, 0, stream>>>(kwh, Kt, k_b, kpw);
    proj_gemm<1><<<dim3(8, 4, BS), 256, 0, stream>>>(Vt, vwh, v_b, vpw);
  } else {
    // fallback: old fused path (32 MiB workspace)
    fused_proj<0><<<dim3(4, 8, BS), 256, 0, stream>>>(k_w, k_in, k_b, kpw);
    fused_proj<1><<<dim3(8, 4, BS), 256, 0, stream>>>(v_w, v_in, v_b, vpw);
  }
  attn_kernel<<<dim3(BS * NH, SL / 256), 256, 0, stream>>>(q, kpw, vpw, gamma, gbns, mask, out);
}